// Round 13
// baseline (630.508 us; speedup 1.0000x reference)
//
#include <hip/hip_runtime.h>

typedef __attribute__((ext_vector_type(8))) short bf16x8;
typedef __attribute__((ext_vector_type(4))) float f32x4;
typedef __attribute__((ext_vector_type(16))) float f32x16;

__device__ __forceinline__ ushort f2bf(float x) {
  union { float f; unsigned u; } c; c.f = x;
  unsigned u = c.u;
  u += 0x7fffu + ((u >> 16) & 1u);
  return (ushort)(u >> 16);
}

__device__ __forceinline__ unsigned cvt_pk_bf16(float lo, float hi) {
  unsigned r;
  asm("v_cvt_pk_bf16_f32 %0, %1, %2" : "=v"(r) : "v"(lo), "v"(hi));
  return r;
}

__device__ __forceinline__ void gl_lds16(const void* g, void* s) {
  __builtin_amdgcn_global_load_lds(
      (const __attribute__((address_space(1))) unsigned*)g,
      (__attribute__((address_space(3))) unsigned*)s, 16, 0, 0);
}

// ---------------------------------------------------------------------------
// W1[128][256] -> Wt1[256][128] bf16 ; W2[256][256] -> Wt2[256][256] bf16
// ---------------------------------------------------------------------------
__global__ __launch_bounds__(256) void prep_w(
    const float* __restrict__ W1, const float* __restrict__ W2,
    ushort* __restrict__ Wt1, ushort* __restrict__ Wt2)
{
  int idx = blockIdx.x * 256 + threadIdx.x;   // 0..65535
  if (idx < 32768) {
    int k = idx >> 8, n = idx & 255;
    Wt1[n * 128 + k] = f2bf(W1[idx]);
  }
  {
    int k = idx >> 8, n = idx & 255;
    Wt2[n * 256 + k] = f2bf(W2[idx]);
  }
}

// ---------------------------------------------------------------------------
// Fused prep (r10, measured-good): X read once; emits Xt transpose, then
// h = relu(X@W1+b1) via LDS handoff, then f = relu(h@W2+b2).
// ---------------------------------------------------------------------------
__global__ __launch_bounds__(256) void fused_mlp(
    const float* __restrict__ A, const float* __restrict__ Bm,
    const ushort* __restrict__ Wt1, const float* __restrict__ b1,
    const ushort* __restrict__ Wt2, const float* __restrict__ b2,
    ushort* __restrict__ fA, ushort* __restrict__ fB,
    ushort* __restrict__ At, ushort* __restrict__ Bt)
{
  const float* X = blockIdx.y ? Bm : A;
  ushort* outF = blockIdx.y ? fB : fA;
  ushort* outT = blockIdx.y ? Bt : At;

  __shared__ ushort Xl[64][136];
  __shared__ ushort Hl[64][264];

  int tid = threadIdx.x;
  int l = tid & 63, w = tid >> 6;
  int rowbase = blockIdx.x * 64 + w * 16;

  bf16x8 xf[4];
  {
    int r = rowbase + (l & 15);
    int koff = (l >> 4) * 8;
    const float* Xp = X + (size_t)r * 128 + koff;
#pragma unroll
    for (int kc = 0; kc < 4; ++kc) {
      float4 a = *(const float4*)(Xp + kc * 32);
      float4 c = *(const float4*)(Xp + kc * 32 + 4);
      bf16x8 v;
      v[0] = (short)f2bf(a.x); v[1] = (short)f2bf(a.y);
      v[2] = (short)f2bf(a.z); v[3] = (short)f2bf(a.w);
      v[4] = (short)f2bf(c.x); v[5] = (short)f2bf(c.y);
      v[6] = (short)f2bf(c.z); v[7] = (short)f2bf(c.w);
      xf[kc] = v;
      *(bf16x8*)&Xl[w * 16 + (l & 15)][koff + kc * 32] = v;
    }
  }

  f32x4 acc1[16];
#pragma unroll
  for (int i = 0; i < 16; ++i) acc1[i] = (f32x4){0.f, 0.f, 0.f, 0.f};
#pragma unroll
  for (int kc = 0; kc < 4; ++kc) {
#pragma unroll
    for (int nf = 0; nf < 16; ++nf) {
      bf16x8 bfv = *(const bf16x8*)&Wt1[(size_t)(nf * 16 + (l & 15)) * 128 + kc * 32 + (l >> 4) * 8];
      acc1[nf] = __builtin_amdgcn_mfma_f32_16x16x32_bf16(xf[kc], bfv, acc1[nf], 0, 0, 0);
    }
  }
  __syncthreads();

  {
    int b = (blockIdx.x * 64) >> 12;
    int m0 = (blockIdx.x * 64) & 4095;
    int d = tid >> 1, mh = (tid & 1) * 32;
    ushort* op = outT + ((size_t)b * 128 + d) * 4096 + m0 + mh;
#pragma unroll
    for (int g = 0; g < 4; ++g) {
      bf16x8 v;
#pragma unroll
      for (int j = 0; j < 8; ++j) v[j] = (short)Xl[mh + g * 8 + j][d];
      *(bf16x8*)(op + g * 8) = v;
    }
  }

#pragma unroll
  for (int nf = 0; nf < 16; ++nf) {
    int col = nf * 16 + (l & 15);
    float bv = b1[col];
#pragma unroll
    for (int i = 0; i < 4; ++i) {
      float v = fmaxf(acc1[nf][i] + bv, 0.f);
      Hl[w * 16 + (l >> 4) * 4 + i][col] = f2bf(v);
    }
  }
  __syncthreads();

  bf16x8 hf[8];
  {
    int koff = (l >> 4) * 8;
#pragma unroll
    for (int kc = 0; kc < 8; ++kc)
      hf[kc] = *(const bf16x8*)&Hl[w * 16 + (l & 15)][koff + kc * 32];
  }
  f32x4 acc2[16];
#pragma unroll
  for (int i = 0; i < 16; ++i) acc2[i] = (f32x4){0.f, 0.f, 0.f, 0.f};
#pragma unroll
  for (int kc = 0; kc < 8; ++kc) {
#pragma unroll
    for (int nf = 0; nf < 16; ++nf) {
      bf16x8 bfv = *(const bf16x8*)&Wt2[(size_t)(nf * 16 + (l & 15)) * 256 + kc * 32 + (l >> 4) * 8];
      acc2[nf] = __builtin_amdgcn_mfma_f32_16x16x32_bf16(hf[kc], bfv, acc2[nf], 0, 0, 0);
    }
  }
#pragma unroll
  for (int nf = 0; nf < 16; ++nf) {
    int col = nf * 16 + (l & 15);
    float bv = b2[col];
#pragma unroll
    for (int i = 0; i < 4; ++i) {
      float v = fmaxf(acc2[nf][i] + bv, 0.f);
      outF[(size_t)(rowbase + (l >> 4) * 4 + i) * 256 + col] = f2bf(v);
    }
  }
}

// ---------------------------------------------------------------------------
// Flash partial pass, 8-wave blocks for 16 waves/CU. Waves = (qg in {0..3},
// kw in {0,1}); block = 128 q-rows x 1024 keys (kchunk kc of split-K-4).
// Inner loop = r10 VERBATIM: dbuf 64-key LDS tiles, stage-AFTER-barrier
// (single-buffer pattern is empirically broken: r11/r12), kw splits each
// tile 2x32, 5-bit XOR swizzle. kw-partner merge (r10 verbatim, pw=w^1),
// then NORMALIZED f16 partial store (acc/l in [-4.8,4.8]) + f32 (m,l).
// Grid (16,32) = 512 blocks/pass; LDS 69.6 KB -> 2 blocks/CU = 16 waves/CU.
// ---------------------------------------------------------------------------
__global__ __launch_bounds__(512, 4) void flashV(
    const ushort* __restrict__ fA, const ushort* __restrict__ fB,
    const ushort* __restrict__ At, const ushort* __restrict__ Bt,
    _Float16* __restrict__ Pf16, float* __restrict__ pML, int pass)
{
  int bx = blockIdx.x;                 // b*4 + kc
  int b = bx >> 2, kc = bx & 3;
  int qblk = blockIdx.y;               // 0..31 (128 rows each)
  const ushort* fQ = pass ? fB : fA;
  const ushort* fK = pass ? fA : fB;
  const ushort* Vg = pass ? At : Bt;
  _Float16* P = Pf16 + (size_t)kc * 2097152 + (size_t)b * 524288;
  float* pml = pML + ((size_t)kc * 4 + b) * 8192;   // [m:4096][l:4096]

  __shared__ ushort Kl[2][16384];      // 64 KB dbuf (float-view for merge)
  __shared__ float mlsh[1024];         // per-wave (m,l) exchange, 4 KB

  int tid = threadIdx.x;
  int l = tid & 63, w = tid >> 6;      // 8 waves
  int l31 = l & 31, g5 = l >> 5;
  int qg = w >> 1, kw = w & 1;

  const size_t fkbase = (size_t)b * 4096 * 256;
  const size_t vgbase = (size_t)b * 128 * 4096;
  const int key0 = kc * 1024;

  // LDS[row][g] = G[row][g ^ (row&31)]; 8 waves stage 8 rows each (linear).
  auto stage_k = [&](int t_, int buf_) {
    const ushort* kp = fK + fkbase + (size_t)(key0 + t_ * 64) * 256;
    ushort* lb = &Kl[buf_][0] + w * 2048;
#pragma unroll
    for (int s = 0; s < 4; ++s) {
      int row = w * 8 + s * 2 + g5;
      int gs = l31 ^ (row & 31);
      gl_lds16(kp + (size_t)row * 256 + gs * 8, lb + s * 512);
    }
  };

  // Q regs: B-frag (col = l31 -> qrow, h = kq*16 + g5*8 + j)
  bf16x8 q[16];
  {
    const ushort* qp = fQ + fkbase
        + (size_t)(qblk * 128 + qg * 32 + l31) * 256 + g5 * 8;
#pragma unroll
    for (int kq = 0; kq < 16; ++kq) q[kq] = *(const bf16x8*)(qp + kq * 16);
  }

  f32x16 acc_o0 = {}, acc_o1 = {}, acc_o2 = {}, acc_o3 = {};
  float m_run = -INFINITY, l_run = 0.f;

  stage_k(0, 0);

  for (int t = 0; t < 16; ++t) {
    int cur = t & 1;
    __syncthreads();               // staged K[t] drained; prev reads done
    if (t < 15) stage_k(t + 1, cur ^ 1);

    // V^T loads (L2): B-frag col = l31 -> d-local, k = key-local
    bf16x8 vv[2][4];
#pragma unroll
    for (int dblk = 0; dblk < 4; ++dblk) {
      const ushort* vp = Vg + vgbase + (size_t)(dblk * 32 + l31) * 4096
                         + key0 + t * 64 + kw * 32 + g5 * 8;
      vv[0][dblk] = *(const bf16x8*)(vp);
      vv[1][dblk] = *(const bf16x8*)(vp + 16);
    }

    // QK^T swapped: S^T[key][qrow] = mfma(A=K, B=Q). 2 indep chains.
    const ushort* kbuf = &Kl[cur][0];
    int krow = kw * 32 + l31;                   // krow & 31 == l31
    f32x16 s0 = {}, s1 = {};
#pragma unroll
    for (int kq = 0; kq < 8; ++kq) {
      bf16x8 a0 = *(const bf16x8*)&kbuf[krow * 256 + (((4 * kq + g5)     ^ l31) * 8)];
      bf16x8 a1 = *(const bf16x8*)&kbuf[krow * 256 + (((4 * kq + 2 + g5) ^ l31) * 8)];
      s0 = __builtin_amdgcn_mfma_f32_32x32x16_bf16(a0, q[2 * kq],     s0, 0, 0, 0);
      s1 = __builtin_amdgcn_mfma_f32_32x32x16_bf16(a1, q[2 * kq + 1], s1, 0, 0, 0);
    }

    // lane: qrow = l31; key-local(r,g5) = (r&3) + 8*(r>>2) + 4*g5
    float sv[16];
#pragma unroll
    for (int r = 0; r < 16; ++r) sv[r] = s0[r] + s1[r];

    float pmax = sv[0];
#pragma unroll
    for (int r = 1; r < 16; ++r) pmax = fmaxf(pmax, sv[r]);
    pmax = fmaxf(pmax, __shfl_xor(pmax, 32));

    if (!__all(pmax <= m_run + 8.f)) {       // rare: t=0 / overflow risk only
      float mnew = fmaxf(m_run, pmax);
      float sc = __expf(m_run - mnew);
      l_run *= sc;
#pragma unroll
      for (int r = 0; r < 16; ++r) {
        float scr = __shfl(sc, (r & 3) + 8 * (r >> 2) + 4 * g5);
        acc_o0[r] *= scr; acc_o1[r] *= scr; acc_o2[r] *= scr; acc_o3[r] *= scr;
      }
      m_run = mnew;
    }

    float p[16], psum = 0.f;
#pragma unroll
    for (int r = 0; r < 16; ++r) {
      p[r] = __expf(sv[r] - m_run);
      psum += p[r];
    }
    l_run += psum + __shfl_xor(psum, 32);

    // pack P pairs: pk[r2][h] covers key-locals 4*(2*r2 + g5) + {0..3}
    unsigned pk[4][2];
#pragma unroll
    for (int r2 = 0; r2 < 4; ++r2) {
      pk[r2][0] = cvt_pk_bf16(p[4 * r2 + 0], p[4 * r2 + 1]);
      pk[r2][1] = cvt_pk_bf16(p[4 * r2 + 2], p[4 * r2 + 3]);
    }

    // exchange halves -> PV A-frags; PV MFMAs
#pragma unroll
    for (int kblk = 0; kblk < 2; ++kblk) {
      int r2a = 2 * kblk, r2b = r2a + 1;
      unsigned la0 = pk[r2a][0], la1 = pk[r2a][1];
      unsigned lb0 = pk[r2b][0], lb1 = pk[r2b][1];
      unsigned s0w = g5 ? la0 : lb0, s1w = g5 ? la1 : lb1;
      unsigned rc0 = (unsigned)__shfl_xor((int)s0w, 32);
      unsigned rc1 = (unsigned)__shfl_xor((int)s1w, 32);
      union { unsigned u[4]; bf16x8 v; } pf;
      pf.u[0] = g5 ? rc0 : la0;  pf.u[1] = g5 ? rc1 : la1;
      pf.u[2] = g5 ? lb0 : rc0;  pf.u[3] = g5 ? lb1 : rc1;
      acc_o0 = __builtin_amdgcn_mfma_f32_32x32x16_bf16(pf.v, vv[kblk][0], acc_o0, 0, 0, 0);
      acc_o1 = __builtin_amdgcn_mfma_f32_32x32x16_bf16(pf.v, vv[kblk][1], acc_o1, 0, 0, 0);
      acc_o2 = __builtin_amdgcn_mfma_f32_32x32x16_bf16(pf.v, vv[kblk][2], acc_o2, 0, 0, 0);
      acc_o3 = __builtin_amdgcn_mfma_f32_32x32x16_bf16(pf.v, vv[kblk][3], acc_o3, 0, 0, 0);
    }
  }

  // ---- merge kw partners (pw = w^1) through LDS, store NORMALIZED f16 ----
  __syncthreads();                 // all K reads done; Kl reusable
  mlsh[w * 128 + l] = m_run;
  mlsh[w * 128 + 64 + l] = l_run;
  float* accsh = (float*)&Kl[0][0];  // 16384 floats
  {
    float* sa = accsh + w * 2048;
    const f32x16& send0 = kw ? acc_o0 : acc_o2;
    const f32x16& send1 = kw ? acc_o1 : acc_o3;
#pragma unroll
    for (int r = 0; r < 16; ++r) {
      sa[r * 64 + l] = send0[r];
      sa[1024 + r * 64 + l] = send1[r];
    }
  }
  __syncthreads();
  {
    int pw = w ^ 1;
    float m1 = mlsh[pw * 128 + l];
    float l1 = mlsh[pw * 128 + 64 + l];
    float M = fmaxf(m_run, m1);
    float a0 = __expf(m_run - M), a1 = __expf(m1 - M);
    float lsum = l_run * a0 + l1 * a1;
    float inv = 1.f / lsum;
    const float* sp = accsh + pw * 2048;
    const f32x16& keep0 = kw ? acc_o2 : acc_o0;
    const f32x16& keep1 = kw ? acc_o3 : acc_o1;
    int dbase = kw ? 64 : 0;
    int qr = qblk * 128 + qg * 32;
    if (kw == 0 && g5 == 0) {          // one lane per q-row writes (m,l)
      pml[qr + l31] = M;
      pml[4096 + qr + l31] = lsum;
    }
#pragma unroll
    for (int r = 0; r < 16; ++r) {
      int rowl = (r & 3) + 8 * (r >> 2) + 4 * g5;
      float invr = __shfl(inv, rowl);
      float a0r = __shfl(a0, rowl);
      float a1r = __shfl(a1, rowl);
      _Float16* op = P + (size_t)(qr + rowl) * 128 + dbase + l31;
      op[0]  = (_Float16)((keep0[r] * a0r + sp[r * 64 + l] * a1r) * invr);
      op[32] = (_Float16)((keep1[r] * a0r + sp[1024 + r * 64 + l] * a1r) * invr);
    }
  }
}

// ---------------------------------------------------------------------------
// Combine the 4 kchunk partials: out = sum_kc w_kc*Obar_kc / sum_kc w_kc,
// w_kc = exp(m_kc - M) * l_kc. Each thread owns 4 consecutive floats.
// ---------------------------------------------------------------------------
__global__ __launch_bounds__(256) void kmerge4(
    float* __restrict__ outp, const _Float16* __restrict__ Pf16,
    const float* __restrict__ pML)
{
  size_t i = ((size_t)blockIdx.x * 256 + threadIdx.x) * 4;  // [0, 2M)
  int fr = (int)(i >> 7);            // b*4096 + row
  int b = fr >> 12, row = fr & 4095;

  float m0 = pML[((size_t)0 * 4 + b) * 8192 + row];
  float m1 = pML[((size_t)1 * 4 + b) * 8192 + row];
  float m2 = pML[((size_t)2 * 4 + b) * 8192 + row];
  float m3 = pML[((size_t)3 * 4 + b) * 8192 + row];
  float M = fmaxf(fmaxf(m0, m1), fmaxf(m2, m3));
  float w0 = __expf(m0 - M) * pML[((size_t)0 * 4 + b) * 8192 + 4096 + row];
  float w1 = __expf(m1 - M) * pML[((size_t)1 * 4 + b) * 8192 + 4096 + row];
  float w2 = __expf(m2 - M) * pML[((size_t)2 * 4 + b) * 8192 + 4096 + row];
  float w3 = __expf(m3 - M) * pML[((size_t)3 * 4 + b) * 8192 + 4096 + row];
  float inv = 1.f / (w0 + w1 + w2 + w3);

  typedef __attribute__((ext_vector_type(4))) _Float16 f16x4;
  f16x4 p0 = *(const f16x4*)(Pf16 + 0 * 2097152 + i);
  f16x4 p1 = *(const f16x4*)(Pf16 + 1 * 2097152 + i);
  f16x4 p2 = *(const f16x4*)(Pf16 + 2 * 2097152 + i);
  f16x4 p3 = *(const f16x4*)(Pf16 + 3 * 2097152 + i);
  f32x4 r;
#pragma unroll
  for (int j = 0; j < 4; ++j)
    r[j] = (w0 * (float)p0[j] + w1 * (float)p1[j] +
            w2 * (float)p2[j] + w3 * (float)p3[j]) * inv;
  *(f32x4*)(outp + i) = r;
}

// ---------------------------------------------------------------------------
extern "C" void kernel_launch(void* const* d_in, const int* in_sizes, int n_in,
                              void* d_out, int out_size, void* d_ws, size_t ws_size,
                              hipStream_t stream) {
  const float* A  = (const float*)d_in[0];
  const float* Bm = (const float*)d_in[1];
  const float* W1 = (const float*)d_in[2];
  const float* b1 = (const float*)d_in[3];
  const float* W2 = (const float*)d_in[4];
  const float* b2 = (const float*)d_in[5];
  float* out = (float*)d_out;

  // ws (ushort units): fA,fB [16384][256]; At,Bt [4][128][4096]; Wt1,Wt2;
  // Pf16 (4 x 2M f16 = 16MB); pML (128K f32 = 512KB). Total ~40.9 MB.
  ushort* ws = (ushort*)d_ws;
  ushort* fA  = ws;
  ushort* fB  = fA + 4194304;
  ushort* At  = fB + 4194304;
  ushort* Bt  = At + 2097152;
  ushort* Wt1 = Bt + 2097152;
  ushort* Wt2 = Wt1 + 32768;
  _Float16* Pf16 = (_Float16*)(Wt2 + 65536);
  float* pML = (float*)(Pf16 + 8388608);

  prep_w<<<256, 256, 0, stream>>>(W1, W2, Wt1, Wt2);
  fused_mlp<<<dim3(256, 2), 256, 0, stream>>>(A, Bm, Wt1, b1, Wt2, b2,
                                              fA, fB, At, Bt);
  flashV<<<dim3(16, 32), 512, 0, stream>>>(fA, fB, At, Bt, Pf16, pML, 0);
  kmerge4<<<2048, 256, 0, stream>>>(out, Pf16, pML);
  flashV<<<dim3(16, 32), 512, 0, stream>>>(fA, fB, At, Bt, Pf16, pML, 1);
  kmerge4<<<2048, 256, 0, stream>>>(out + 2097152, Pf16, pML);
}

// Round 14
// 233.292 us; speedup vs baseline: 2.7027x; 2.7027x over previous
//
#include <hip/hip_runtime.h>

typedef __attribute__((ext_vector_type(8))) short bf16x8;
typedef __attribute__((ext_vector_type(4))) float f32x4;
typedef __attribute__((ext_vector_type(16))) float f32x16;

__device__ __forceinline__ ushort f2bf(float x) {
  union { float f; unsigned u; } c; c.f = x;
  unsigned u = c.u;
  u += 0x7fffu + ((u >> 16) & 1u);
  return (ushort)(u >> 16);
}

__device__ __forceinline__ unsigned cvt_pk_bf16(float lo, float hi) {
  unsigned r;
  asm("v_cvt_pk_bf16_f32 %0, %1, %2" : "=v"(r) : "v"(lo), "v"(hi));
  return r;
}

__device__ __forceinline__ void gl_lds16(const void* g, void* s) {
  __builtin_amdgcn_global_load_lds(
      (const __attribute__((address_space(1))) unsigned*)g,
      (__attribute__((address_space(3))) unsigned*)s, 16, 0, 0);
}

// ---------------------------------------------------------------------------
// W1[128][256] -> Wt1[256][128] bf16 ; W2[256][256] -> Wt2[256][256] bf16
// ---------------------------------------------------------------------------
__global__ __launch_bounds__(256) void prep_w(
    const float* __restrict__ W1, const float* __restrict__ W2,
    ushort* __restrict__ Wt1, ushort* __restrict__ Wt2)
{
  int idx = blockIdx.x * 256 + threadIdx.x;   // 0..65535
  if (idx < 32768) {
    int k = idx >> 8, n = idx & 255;
    Wt1[n * 128 + k] = f2bf(W1[idx]);
  }
  {
    int k = idx >> 8, n = idx & 255;
    Wt2[n * 256 + k] = f2bf(W2[idx]);
  }
}

// ---------------------------------------------------------------------------
// Fused prep (r10, measured-good): X read once; emits Xt transpose, then
// h = relu(X@W1+b1) via LDS handoff, then f = relu(h@W2+b2).
// ---------------------------------------------------------------------------
__global__ __launch_bounds__(256) void fused_mlp(
    const float* __restrict__ A, const float* __restrict__ Bm,
    const ushort* __restrict__ Wt1, const float* __restrict__ b1,
    const ushort* __restrict__ Wt2, const float* __restrict__ b2,
    ushort* __restrict__ fA, ushort* __restrict__ fB,
    ushort* __restrict__ At, ushort* __restrict__ Bt)
{
  const float* X = blockIdx.y ? Bm : A;
  ushort* outF = blockIdx.y ? fB : fA;
  ushort* outT = blockIdx.y ? Bt : At;

  __shared__ ushort Xl[64][136];
  __shared__ ushort Hl[64][264];

  int tid = threadIdx.x;
  int l = tid & 63, w = tid >> 6;
  int rowbase = blockIdx.x * 64 + w * 16;

  bf16x8 xf[4];
  {
    int r = rowbase + (l & 15);
    int koff = (l >> 4) * 8;
    const float* Xp = X + (size_t)r * 128 + koff;
#pragma unroll
    for (int kc = 0; kc < 4; ++kc) {
      float4 a = *(const float4*)(Xp + kc * 32);
      float4 c = *(const float4*)(Xp + kc * 32 + 4);
      bf16x8 v;
      v[0] = (short)f2bf(a.x); v[1] = (short)f2bf(a.y);
      v[2] = (short)f2bf(a.z); v[3] = (short)f2bf(a.w);
      v[4] = (short)f2bf(c.x); v[5] = (short)f2bf(c.y);
      v[6] = (short)f2bf(c.z); v[7] = (short)f2bf(c.w);
      xf[kc] = v;
      *(bf16x8*)&Xl[w * 16 + (l & 15)][koff + kc * 32] = v;
    }
  }

  f32x4 acc1[16];
#pragma unroll
  for (int i = 0; i < 16; ++i) acc1[i] = (f32x4){0.f, 0.f, 0.f, 0.f};
#pragma unroll
  for (int kc = 0; kc < 4; ++kc) {
#pragma unroll
    for (int nf = 0; nf < 16; ++nf) {
      bf16x8 bfv = *(const bf16x8*)&Wt1[(size_t)(nf * 16 + (l & 15)) * 128 + kc * 32 + (l >> 4) * 8];
      acc1[nf] = __builtin_amdgcn_mfma_f32_16x16x32_bf16(xf[kc], bfv, acc1[nf], 0, 0, 0);
    }
  }
  __syncthreads();

  {
    int b = (blockIdx.x * 64) >> 12;
    int m0 = (blockIdx.x * 64) & 4095;
    int d = tid >> 1, mh = (tid & 1) * 32;
    ushort* op = outT + ((size_t)b * 128 + d) * 4096 + m0 + mh;
#pragma unroll
    for (int g = 0; g < 4; ++g) {
      bf16x8 v;
#pragma unroll
      for (int j = 0; j < 8; ++j) v[j] = (short)Xl[mh + g * 8 + j][d];
      *(bf16x8*)(op + g * 8) = v;
    }
  }

#pragma unroll
  for (int nf = 0; nf < 16; ++nf) {
    int col = nf * 16 + (l & 15);
    float bv = b1[col];
#pragma unroll
    for (int i = 0; i < 4; ++i) {
      float v = fmaxf(acc1[nf][i] + bv, 0.f);
      Hl[w * 16 + (l >> 4) * 4 + i][col] = f2bf(v);
    }
  }
  __syncthreads();

  bf16x8 hf[8];
  {
    int koff = (l >> 4) * 8;
#pragma unroll
    for (int kc = 0; kc < 8; ++kc)
      hf[kc] = *(const bf16x8*)&Hl[w * 16 + (l & 15)][koff + kc * 32];
  }
  f32x4 acc2[16];
#pragma unroll
  for (int i = 0; i < 16; ++i) acc2[i] = (f32x4){0.f, 0.f, 0.f, 0.f};
#pragma unroll
  for (int kc = 0; kc < 8; ++kc) {
#pragma unroll
    for (int nf = 0; nf < 16; ++nf) {
      bf16x8 bfv = *(const bf16x8*)&Wt2[(size_t)(nf * 16 + (l & 15)) * 256 + kc * 32 + (l >> 4) * 8];
      acc2[nf] = __builtin_amdgcn_mfma_f32_16x16x32_bf16(hf[kc], bfv, acc2[nf], 0, 0, 0);
    }
  }
#pragma unroll
  for (int nf = 0; nf < 16; ++nf) {
    int col = nf * 16 + (l & 15);
    float bv = b2[col];
#pragma unroll
    for (int i = 0; i < 4; ++i) {
      float v = fmaxf(acc2[nf][i] + bv, 0.f);
      outF[(size_t)(rowbase + (l >> 4) * 4 + i) * 256 + col] = f2bf(v);
    }
  }
}

// ---------------------------------------------------------------------------
// Flash pass — r3/r10 structure VERBATIM (best measured: 189.7 us; profile
// reproduced bit-identically across rounds). Split-K across waves: block =
// 4 waves = (qw, kw); 64 q-rows; wave = 32 q-rows x 32 keys of each 64-key
// LDS tile (dbuf, global_load_lds, 3-bit XOR swizzle). Grid (8, 64) =
// 512 blocks -> 2 blocks/CU, XCD-pure x=(pass,b) mapping (the ONLY grid
// that preserves the 20 MB FETCH economy — r5/r7/r13 all thrash without
// it). End merge of (m,l,acc) between kw partners via LDS.
// ---------------------------------------------------------------------------
__global__ __launch_bounds__(256, 2) void flash2(
    const ushort* __restrict__ fA, const ushort* __restrict__ fB,
    const ushort* __restrict__ At, const ushort* __restrict__ Bt,
    float* __restrict__ out)
{
  int bp = blockIdx.x;
  int pass = bp >> 2, b = bp & 3;
  int qbase = blockIdx.y * 64;
  const ushort* fQ = pass ? fB : fA;
  const ushort* fK = pass ? fA : fB;
  const ushort* Vg = pass ? At : Bt;
  float* O = out + (size_t)pass * (4u * 4096 * 128) + (size_t)b * 4096 * 128;

  __shared__ ushort Kl[2][64 * 256];   // 64 KB (also reused for final merge)

  int tid = threadIdx.x;
  int l = tid & 63, w = tid >> 6;
  int l31 = l & 31, g5 = l >> 5;
  int qw = w & 1, kw = w >> 1;

  const size_t fkbase = (size_t)b * 4096 * 256;
  const size_t vgbase = (size_t)b * 128 * 4096;

  auto stage_k = [&](int t_, int buf_) {
    const ushort* kp = fK + fkbase + (size_t)t_ * 16384;
    ushort* lb = &Kl[buf_][0] + w * 4096;
#pragma unroll
    for (int s = 0; s < 8; ++s) {
      int row = w * 16 + s * 2 + g5;
      int gs = l31 ^ (row & 7);
      gl_lds16(kp + (size_t)row * 256 + gs * 8, lb + s * 512);
    }
  };

  // Q regs: B-frag (col = l31 -> qrow, k = kc*16 + g5*8 + j)
  bf16x8 q[16];
  {
    const ushort* qp = fQ + fkbase + (size_t)(qbase + qw * 32 + l31) * 256 + g5 * 8;
#pragma unroll
    for (int kc = 0; kc < 16; ++kc) q[kc] = *(const bf16x8*)(qp + kc * 16);
  }

  f32x16 acc_o0 = {}, acc_o1 = {}, acc_o2 = {}, acc_o3 = {};
  float m_run = -INFINITY, l_run = 0.f;

  stage_k(0, 0);

  for (int t = 0; t < 64; ++t) {
    int cur = t & 1;
    __syncthreads();               // staged K[t] drained; prev reads done
    if (t < 63) stage_k(t + 1, cur ^ 1);

    // V^T loads (L2): B-frag col = l31 -> d-local, k = key-local
    bf16x8 vv[2][4];
#pragma unroll
    for (int dblk = 0; dblk < 4; ++dblk) {
      const ushort* vp = Vg + vgbase + (size_t)(dblk * 32 + l31) * 4096
                         + t * 64 + kw * 32 + g5 * 8;
#pragma unroll
      for (int kblk = 0; kblk < 2; ++kblk)
        vv[kblk][dblk] = *(const bf16x8*)(vp + kblk * 16);
    }

    // QK^T swapped: S^T[key][qrow] = mfma(A=K, B=Q). 2 indep chains.
    const ushort* kbuf = &Kl[cur][0];
    int krow = kw * 32 + l31;
    int sx = l31 & 7;
    f32x16 s0 = {}, s1 = {};
#pragma unroll
    for (int kc = 0; kc < 8; ++kc) {
      bf16x8 a0 = *(const bf16x8*)&kbuf[krow * 256 + (((4 * kc + g5) ^ sx) * 8)];
      bf16x8 a1 = *(const bf16x8*)&kbuf[krow * 256 + (((4 * kc + 2 + g5) ^ sx) * 8)];
      s0 = __builtin_amdgcn_mfma_f32_32x32x16_bf16(a0, q[2 * kc],     s0, 0, 0, 0);
      s1 = __builtin_amdgcn_mfma_f32_32x32x16_bf16(a1, q[2 * kc + 1], s1, 0, 0, 0);
    }

    // lane: qrow = l31; key-local(r,g5) = (r&3) + 8*(r>>2) + 4*g5  in [0,32)
    float sv[16];
#pragma unroll
    for (int r = 0; r < 16; ++r) sv[r] = s0[r] + s1[r];

    float pmax = sv[0];
#pragma unroll
    for (int r = 1; r < 16; ++r) pmax = fmaxf(pmax, sv[r]);
    pmax = fmaxf(pmax, __shfl_xor(pmax, 32));

    if (!__all(pmax <= m_run + 8.f)) {       // rare (t=0 / overflow risk only)
      float mnew = fmaxf(m_run, pmax);
      float sc = __expf(m_run - mnew);
      l_run *= sc;
#pragma unroll
      for (int r = 0; r < 16; ++r) {
        float scr = __shfl(sc, (r & 3) + 8 * (r >> 2) + 4 * g5);
        acc_o0[r] *= scr; acc_o1[r] *= scr; acc_o2[r] *= scr; acc_o3[r] *= scr;
      }
      m_run = mnew;
    }

    float p[16], psum = 0.f;
#pragma unroll
    for (int r = 0; r < 16; ++r) {
      p[r] = __expf(sv[r] - m_run);
      psum += p[r];
    }
    l_run += psum + __shfl_xor(psum, 32);

    // pack P pairs: pk[r2][h] covers key-locals 4*(2*r2 + g5) + {0..3}
    unsigned pk[4][2];
#pragma unroll
    for (int r2 = 0; r2 < 4; ++r2) {
      pk[r2][0] = cvt_pk_bf16(p[4 * r2 + 0], p[4 * r2 + 1]);
      pk[r2][1] = cvt_pk_bf16(p[4 * r2 + 2], p[4 * r2 + 3]);
    }

    // exchange halves -> PV A-frags; PV MFMAs
#pragma unroll
    for (int kblk = 0; kblk < 2; ++kblk) {
      int r2a = 2 * kblk, r2b = r2a + 1;
      unsigned la0 = pk[r2a][0], la1 = pk[r2a][1];
      unsigned lb0 = pk[r2b][0], lb1 = pk[r2b][1];
      unsigned s0w = g5 ? la0 : lb0, s1w = g5 ? la1 : lb1;
      unsigned rc0 = (unsigned)__shfl_xor((int)s0w, 32);
      unsigned rc1 = (unsigned)__shfl_xor((int)s1w, 32);
      union { unsigned u[4]; bf16x8 v; } pf;
      pf.u[0] = g5 ? rc0 : la0;  pf.u[1] = g5 ? rc1 : la1;
      pf.u[2] = g5 ? lb0 : rc0;  pf.u[3] = g5 ? lb1 : rc1;
      acc_o0 = __builtin_amdgcn_mfma_f32_32x32x16_bf16(pf.v, vv[kblk][0], acc_o0, 0, 0, 0);
      acc_o1 = __builtin_amdgcn_mfma_f32_32x32x16_bf16(pf.v, vv[kblk][1], acc_o1, 0, 0, 0);
      acc_o2 = __builtin_amdgcn_mfma_f32_32x32x16_bf16(pf.v, vv[kblk][2], acc_o2, 0, 0, 0);
      acc_o3 = __builtin_amdgcn_mfma_f32_32x32x16_bf16(pf.v, vv[kblk][3], acc_o3, 0, 0, 0);
    }
  }

  // ---- merge kw partners through LDS, then store ----
  __syncthreads();                 // all K reads done; Kl reusable
  float* shm = (float*)&Kl[0][0];
  shm[w * 128 + l] = m_run;
  shm[w * 128 + 64 + l] = l_run;
  {
    float* sa = shm + 512 + w * 2048;
    const f32x16& send0 = kw ? acc_o0 : acc_o2;
    const f32x16& send1 = kw ? acc_o1 : acc_o3;
#pragma unroll
    for (int r = 0; r < 16; ++r) {
      sa[r * 64 + l] = send0[r];
      sa[1024 + r * 64 + l] = send1[r];
    }
  }
  __syncthreads();
  {
    int pw = w ^ 2;
    float m1 = shm[pw * 128 + l];
    float l1 = shm[pw * 128 + 64 + l];
    float M = fmaxf(m_run, m1);
    float a0 = __expf(m_run - M), a1 = __expf(m1 - M);
    float inv = 1.f / (l_run * a0 + l1 * a1);
    const float* sp = shm + 512 + pw * 2048;
    const f32x16& keep0 = kw ? acc_o2 : acc_o0;
    const f32x16& keep1 = kw ? acc_o3 : acc_o1;
    int dbase = kw ? 64 : 0;
    int qr = qbase + qw * 32;
#pragma unroll
    for (int r = 0; r < 16; ++r) {
      int rowl = (r & 3) + 8 * (r >> 2) + 4 * g5;
      float invr = __shfl(inv, rowl);
      float a0r = __shfl(a0, rowl);
      float a1r = __shfl(a1, rowl);
      float* op = O + (size_t)(qr + rowl) * 128 + dbase + l31;
      op[0]  = (keep0[r] * a0r + sp[r * 64 + l] * a1r) * invr;
      op[32] = (keep1[r] * a0r + sp[1024 + r * 64 + l] * a1r) * invr;
    }
  }
}

// ---------------------------------------------------------------------------
extern "C" void kernel_launch(void* const* d_in, const int* in_sizes, int n_in,
                              void* d_out, int out_size, void* d_ws, size_t ws_size,
                              hipStream_t stream) {
  const float* A  = (const float*)d_in[0];
  const float* Bm = (const float*)d_in[1];
  const float* W1 = (const float*)d_in[2];
  const float* b1 = (const float*)d_in[3];
  const float* W2 = (const float*)d_in[4];
  const float* b2 = (const float*)d_in[5];
  float* out = (float*)d_out;

  // ws (ushort units): fA,fB [16384][256]; At,Bt [4][128][4096]; Wt1,Wt2
  ushort* ws = (ushort*)d_ws;
  ushort* fA  = ws;
  ushort* fB  = fA + 4194304;
  ushort* At  = fB + 4194304;
  ushort* Bt  = At + 2097152;
  ushort* Wt1 = Bt + 2097152;
  ushort* Wt2 = Wt1 + 32768;     // total ~25.4 MB

  prep_w<<<256, 256, 0, stream>>>(W1, W2, Wt1, Wt2);
  fused_mlp<<<dim3(256, 2), 256, 0, stream>>>(A, Bm, Wt1, b1, Wt2, b2,
                                              fA, fB, At, Bt);
  flash2<<<dim3(8, 64), 256, 0, stream>>>(fA, fB, At, Bt, out);
}

// Round 16
// 232.993 us; speedup vs baseline: 2.7061x; 1.0013x over previous
//
#include <hip/hip_runtime.h>

typedef __attribute__((ext_vector_type(8))) short bf16x8;
typedef __attribute__((ext_vector_type(4))) float f32x4;
typedef __attribute__((ext_vector_type(16))) float f32x16;

__device__ __forceinline__ ushort f2bf(float x) {
  union { float f; unsigned u; } c; c.f = x;
  unsigned u = c.u;
  u += 0x7fffu + ((u >> 16) & 1u);
  return (ushort)(u >> 16);
}

__device__ __forceinline__ unsigned cvt_pk_bf16(float lo, float hi) {
  unsigned r;
  asm("v_cvt_pk_bf16_f32 %0, %1, %2" : "=v"(r) : "v"(lo), "v"(hi));
  return r;
}

__device__ __forceinline__ void gl_lds16(const void* g, void* s) {
  __builtin_amdgcn_global_load_lds(
      (const __attribute__((address_space(1))) unsigned*)g,
      (__attribute__((address_space(3))) unsigned*)s, 16, 0, 0);
}

// ---------------------------------------------------------------------------
// W1[128][256] -> Wt1[256][128] bf16 ; W2[256][256] -> Wt2[256][256] bf16
// ---------------------------------------------------------------------------
__global__ __launch_bounds__(256) void prep_w(
    const float* __restrict__ W1, const float* __restrict__ W2,
    ushort* __restrict__ Wt1, ushort* __restrict__ Wt2)
{
  int idx = blockIdx.x * 256 + threadIdx.x;   // 0..65535
  if (idx < 32768) {
    int k = idx >> 8, n = idx & 255;
    Wt1[n * 128 + k] = f2bf(W1[idx]);
  }
  {
    int k = idx >> 8, n = idx & 255;
    Wt2[n * 256 + k] = f2bf(W2[idx]);
  }
}

// ---------------------------------------------------------------------------
// Fused prep (r10, measured-good): X read once; emits Xt transpose, then
// h = relu(X@W1+b1) via LDS handoff, then f = relu(h@W2+b2).
// ---------------------------------------------------------------------------
__global__ __launch_bounds__(256) void fused_mlp(
    const float* __restrict__ A, const float* __restrict__ Bm,
    const ushort* __restrict__ Wt1, const float* __restrict__ b1,
    const ushort* __restrict__ Wt2, const float* __restrict__ b2,
    ushort* __restrict__ fA, ushort* __restrict__ fB,
    ushort* __restrict__ At, ushort* __restrict__ Bt)
{
  const float* X = blockIdx.y ? Bm : A;
  ushort* outF = blockIdx.y ? fB : fA;
  ushort* outT = blockIdx.y ? Bt : At;

  __shared__ ushort Xl[64][136];
  __shared__ ushort Hl[64][264];

  int tid = threadIdx.x;
  int l = tid & 63, w = tid >> 6;
  int rowbase = blockIdx.x * 64 + w * 16;

  bf16x8 xf[4];
  {
    int r = rowbase + (l & 15);
    int koff = (l >> 4) * 8;
    const float* Xp = X + (size_t)r * 128 + koff;
#pragma unroll
    for (int kc = 0; kc < 4; ++kc) {
      float4 a = *(const float4*)(Xp + kc * 32);
      float4 c = *(const float4*)(Xp + kc * 32 + 4);
      bf16x8 v;
      v[0] = (short)f2bf(a.x); v[1] = (short)f2bf(a.y);
      v[2] = (short)f2bf(a.z); v[3] = (short)f2bf(a.w);
      v[4] = (short)f2bf(c.x); v[5] = (short)f2bf(c.y);
      v[6] = (short)f2bf(c.z); v[7] = (short)f2bf(c.w);
      xf[kc] = v;
      *(bf16x8*)&Xl[w * 16 + (l & 15)][koff + kc * 32] = v;
    }
  }

  f32x4 acc1[16];
#pragma unroll
  for (int i = 0; i < 16; ++i) acc1[i] = (f32x4){0.f, 0.f, 0.f, 0.f};
#pragma unroll
  for (int kc = 0; kc < 4; ++kc) {
#pragma unroll
    for (int nf = 0; nf < 16; ++nf) {
      bf16x8 bfv = *(const bf16x8*)&Wt1[(size_t)(nf * 16 + (l & 15)) * 128 + kc * 32 + (l >> 4) * 8];
      acc1[nf] = __builtin_amdgcn_mfma_f32_16x16x32_bf16(xf[kc], bfv, acc1[nf], 0, 0, 0);
    }
  }
  __syncthreads();

  {
    int b = (blockIdx.x * 64) >> 12;
    int m0 = (blockIdx.x * 64) & 4095;
    int d = tid >> 1, mh = (tid & 1) * 32;
    ushort* op = outT + ((size_t)b * 128 + d) * 4096 + m0 + mh;
#pragma unroll
    for (int g = 0; g < 4; ++g) {
      bf16x8 v;
#pragma unroll
      for (int j = 0; j < 8; ++j) v[j] = (short)Xl[mh + g * 8 + j][d];
      *(bf16x8*)(op + g * 8) = v;
    }
  }

#pragma unroll
  for (int nf = 0; nf < 16; ++nf) {
    int col = nf * 16 + (l & 15);
    float bv = b1[col];
#pragma unroll
    for (int i = 0; i < 4; ++i) {
      float v = fmaxf(acc1[nf][i] + bv, 0.f);
      Hl[w * 16 + (l >> 4) * 4 + i][col] = f2bf(v);
    }
  }
  __syncthreads();

  bf16x8 hf[8];
  {
    int koff = (l >> 4) * 8;
#pragma unroll
    for (int kc = 0; kc < 8; ++kc)
      hf[kc] = *(const bf16x8*)&Hl[w * 16 + (l & 15)][koff + kc * 32];
  }
  f32x4 acc2[16];
#pragma unroll
  for (int i = 0; i < 16; ++i) acc2[i] = (f32x4){0.f, 0.f, 0.f, 0.f};
#pragma unroll
  for (int kc = 0; kc < 8; ++kc) {
#pragma unroll
    for (int nf = 0; nf < 16; ++nf) {
      bf16x8 bfv = *(const bf16x8*)&Wt2[(size_t)(nf * 16 + (l & 15)) * 256 + kc * 32 + (l >> 4) * 8];
      acc2[nf] = __builtin_amdgcn_mfma_f32_16x16x32_bf16(hf[kc], bfv, acc2[nf], 0, 0, 0);
    }
  }
#pragma unroll
  for (int nf = 0; nf < 16; ++nf) {
    int col = nf * 16 + (l & 15);
    float bv = b2[col];
#pragma unroll
    for (int i = 0; i < 4; ++i) {
      float v = fmaxf(acc2[nf][i] + bv, 0.f);
      outF[(size_t)(rowbase + (l >> 4) * 4 + i) * 256 + col] = f2bf(v);
    }
  }
}

// ---------------------------------------------------------------------------
// Flash pass — r3/r10 structure VERBATIM (best measured: 189.7 us; profile
// reproduced bit-identically across rounds). Split-K across waves: block =
// 4 waves = (qw, kw); 64 q-rows; wave = 32 q-rows x 32 keys of each 64-key
// LDS tile (dbuf, global_load_lds, 3-bit XOR swizzle). Grid (8, 64) =
// 512 blocks -> 2 blocks/CU, XCD-pure x=(pass,b) mapping (the ONLY grid
// that preserves the 20 MB FETCH economy — r5/r7/r13 all thrash without
// it). End merge of (m,l,acc) between kw partners via LDS.
// Failure ledger (hardware-refuted alternatives): L2-direct K (r5/r7),
// cross-block split-K (r4/r13), single-buffer LDS (r11/r12), wide blocks
// (r11/r15), vmcnt/sched pins (r6), setprio (r8), chain micro-opts (r9).
// ---------------------------------------------------------------------------
__global__ __launch_bounds__(256, 2) void flash2(
    const ushort* __restrict__ fA, const ushort* __restrict__ fB,
    const ushort* __restrict__ At, const ushort* __restrict__ Bt,
    float* __restrict__ out)
{
  int bp = blockIdx.x;
  int pass = bp >> 2, b = bp & 3;
  int qbase = blockIdx.y * 64;
  const ushort* fQ = pass ? fB : fA;
  const ushort* fK = pass ? fA : fB;
  const ushort* Vg = pass ? At : Bt;
  float* O = out + (size_t)pass * (4u * 4096 * 128) + (size_t)b * 4096 * 128;

  __shared__ ushort Kl[2][64 * 256];   // 64 KB (also reused for final merge)

  int tid = threadIdx.x;
  int l = tid & 63, w = tid >> 6;
  int l31 = l & 31, g5 = l >> 5;
  int qw = w & 1, kw = w >> 1;

  const size_t fkbase = (size_t)b * 4096 * 256;
  const size_t vgbase = (size_t)b * 128 * 4096;

  auto stage_k = [&](int t_, int buf_) {
    const ushort* kp = fK + fkbase + (size_t)t_ * 16384;
    ushort* lb = &Kl[buf_][0] + w * 4096;
#pragma unroll
    for (int s = 0; s < 8; ++s) {
      int row = w * 16 + s * 2 + g5;
      int gs = l31 ^ (row & 7);
      gl_lds16(kp + (size_t)row * 256 + gs * 8, lb + s * 512);
    }
  };

  // Q regs: B-frag (col = l31 -> qrow, k = kc*16 + g5*8 + j)
  bf16x8 q[16];
  {
    const ushort* qp = fQ + fkbase + (size_t)(qbase + qw * 32 + l31) * 256 + g5 * 8;
#pragma unroll
    for (int kc = 0; kc < 16; ++kc) q[kc] = *(const bf16x8*)(qp + kc * 16);
  }

  f32x16 acc_o0 = {}, acc_o1 = {}, acc_o2 = {}, acc_o3 = {};
  float m_run = -INFINITY, l_run = 0.f;

  stage_k(0, 0);

  for (int t = 0; t < 64; ++t) {
    int cur = t & 1;
    __syncthreads();               // staged K[t] drained; prev reads done
    if (t < 63) stage_k(t + 1, cur ^ 1);

    // V^T loads (L2): B-frag col = l31 -> d-local, k = key-local
    bf16x8 vv[2][4];
#pragma unroll
    for (int dblk = 0; dblk < 4; ++dblk) {
      const ushort* vp = Vg + vgbase + (size_t)(dblk * 32 + l31) * 4096
                         + t * 64 + kw * 32 + g5 * 8;
#pragma unroll
      for (int kblk = 0; kblk < 2; ++kblk)
        vv[kblk][dblk] = *(const bf16x8*)(vp + kblk * 16);
    }

    // QK^T swapped: S^T[key][qrow] = mfma(A=K, B=Q). 2 indep chains.
    const ushort* kbuf = &Kl[cur][0];
    int krow = kw * 32 + l31;
    int sx = l31 & 7;
    f32x16 s0 = {}, s1 = {};
#pragma unroll
    for (int kc = 0; kc < 8; ++kc) {
      bf16x8 a0 = *(const bf16x8*)&kbuf[krow * 256 + (((4 * kc + g5) ^ sx) * 8)];
      bf16x8 a1 = *(const bf16x8*)&kbuf[krow * 256 + (((4 * kc + 2 + g5) ^ sx) * 8)];
      s0 = __builtin_amdgcn_mfma_f32_32x32x16_bf16(a0, q[2 * kc],     s0, 0, 0, 0);
      s1 = __builtin_amdgcn_mfma_f32_32x32x16_bf16(a1, q[2 * kc + 1], s1, 0, 0, 0);
    }

    // lane: qrow = l31; key-local(r,g5) = (r&3) + 8*(r>>2) + 4*g5  in [0,32)
    float sv[16];
#pragma unroll
    for (int r = 0; r < 16; ++r) sv[r] = s0[r] + s1[r];

    float pmax = sv[0];
#pragma unroll
    for (int r = 1; r < 16; ++r) pmax = fmaxf(pmax, sv[r]);
    pmax = fmaxf(pmax, __shfl_xor(pmax, 32));

    if (!__all(pmax <= m_run + 8.f)) {       // rare (t=0 / overflow risk only)
      float mnew = fmaxf(m_run, pmax);
      float sc = __expf(m_run - mnew);
      l_run *= sc;
#pragma unroll
      for (int r = 0; r < 16; ++r) {
        float scr = __shfl(sc, (r & 3) + 8 * (r >> 2) + 4 * g5);
        acc_o0[r] *= scr; acc_o1[r] *= scr; acc_o2[r] *= scr; acc_o3[r] *= scr;
      }
      m_run = mnew;
    }

    float p[16], psum = 0.f;
#pragma unroll
    for (int r = 0; r < 16; ++r) {
      p[r] = __expf(sv[r] - m_run);
      psum += p[r];
    }
    l_run += psum + __shfl_xor(psum, 32);

    // pack P pairs: pk[r2][h] covers key-locals 4*(2*r2 + g5) + {0..3}
    unsigned pk[4][2];
#pragma unroll
    for (int r2 = 0; r2 < 4; ++r2) {
      pk[r2][0] = cvt_pk_bf16(p[4 * r2 + 0], p[4 * r2 + 1]);
      pk[r2][1] = cvt_pk_bf16(p[4 * r2 + 2], p[4 * r2 + 3]);
    }

    // exchange halves -> PV A-frags; PV MFMAs
#pragma unroll
    for (int kblk = 0; kblk < 2; ++kblk) {
      int r2a = 2 * kblk, r2b = r2a + 1;
      unsigned la0 = pk[r2a][0], la1 = pk[r2a][1];
      unsigned lb0 = pk[r2b][0], lb1 = pk[r2b][1];
      unsigned s0w = g5 ? la0 : lb0, s1w = g5 ? la1 : lb1;
      unsigned rc0 = (unsigned)__shfl_xor((int)s0w, 32);
      unsigned rc1 = (unsigned)__shfl_xor((int)s1w, 32);
      union { unsigned u[4]; bf16x8 v; } pf;
      pf.u[0] = g5 ? rc0 : la0;  pf.u[1] = g5 ? rc1 : la1;
      pf.u[2] = g5 ? lb0 : rc0;  pf.u[3] = g5 ? lb1 : rc1;
      acc_o0 = __builtin_amdgcn_mfma_f32_32x32x16_bf16(pf.v, vv[kblk][0], acc_o0, 0, 0, 0);
      acc_o1 = __builtin_amdgcn_mfma_f32_32x32x16_bf16(pf.v, vv[kblk][1], acc_o1, 0, 0, 0);
      acc_o2 = __builtin_amdgcn_mfma_f32_32x32x16_bf16(pf.v, vv[kblk][2], acc_o2, 0, 0, 0);
      acc_o3 = __builtin_amdgcn_mfma_f32_32x32x16_bf16(pf.v, vv[kblk][3], acc_o3, 0, 0, 0);
    }
  }

  // ---- merge kw partners through LDS, then store ----
  __syncthreads();                 // all K reads done; Kl reusable
  float* shm = (float*)&Kl[0][0];
  shm[w * 128 + l] = m_run;
  shm[w * 128 + 64 + l] = l_run;
  {
    float* sa = shm + 512 + w * 2048;
    const f32x16& send0 = kw ? acc_o0 : acc_o2;
    const f32x16& send1 = kw ? acc_o1 : acc_o3;
#pragma unroll
    for (int r = 0; r < 16; ++r) {
      sa[r * 64 + l] = send0[r];
      sa[1024 + r * 64 + l] = send1[r];
    }
  }
  __syncthreads();
  {
    int pw = w ^ 2;
    float m1 = shm[pw * 128 + l];
    float l1 = shm[pw * 128 + 64 + l];
    float M = fmaxf(m_run, m1);
    float a0 = __expf(m_run - M), a1 = __expf(m1 - M);
    float inv = 1.f / (l_run * a0 + l1 * a1);
    const float* sp = shm + 512 + pw * 2048;
    const f32x16& keep0 = kw ? acc_o2 : acc_o0;
    const f32x16& keep1 = kw ? acc_o3 : acc_o1;
    int dbase = kw ? 64 : 0;
    int qr = qbase + qw * 32;
#pragma unroll
    for (int r = 0; r < 16; ++r) {
      int rowl = (r & 3) + 8 * (r >> 2) + 4 * g5;
      float invr = __shfl(inv, rowl);
      float a0r = __shfl(a0, rowl);
      float a1r = __shfl(a1, rowl);
      float* op = O + (size_t)(qr + rowl) * 128 + dbase + l31;
      op[0]  = (keep0[r] * a0r + sp[r * 64 + l] * a1r) * invr;
      op[32] = (keep1[r] * a0r + sp[1024 + r * 64 + l] * a1r) * invr;
    }
  }
}

// ---------------------------------------------------------------------------
extern "C" void kernel_launch(void* const* d_in, const int* in_sizes, int n_in,
                              void* d_out, int out_size, void* d_ws, size_t ws_size,
                              hipStream_t stream) {
  const float* A  = (const float*)d_in[0];
  const float* Bm = (const float*)d_in[1];
  const float* W1 = (const float*)d_in[2];
  const float* b1 = (const float*)d_in[3];
  const float* W2 = (const float*)d_in[4];
  const float* b2 = (const float*)d_in[5];
  float* out = (float*)d_out;

  // ws (ushort units): fA,fB [16384][256]; At,Bt [4][128][4096]; Wt1,Wt2
  ushort* ws = (ushort*)d_ws;
  ushort* fA  = ws;
  ushort* fB  = fA + 4194304;
  ushort* At  = fB + 4194304;
  ushort* Bt  = At + 2097152;
  ushort* Wt1 = Bt + 2097152;
  ushort* Wt2 = Wt1 + 32768;     // total ~25.4 MB

  prep_w<<<256, 256, 0, stream>>>(W1, W2, Wt1, Wt2);
  fused_mlp<<<dim3(256, 2), 256, 0, stream>>>(A, Bm, Wt1, b1, Wt2, b2,
                                              fA, fB, At, Bt);
  flash2<<<dim3(8, 64), 256, 0, stream>>>(fA, fB, At, Bt, out);
}